// Round 11
// baseline (280.022 us; speedup 1.0000x reference)
//
#include <hip/hip_runtime.h>

#define FD 128      // feature dim (both layers)
#define BSH 7       // log2(nodes per bucket) = 128 nodes/bucket
#define BPAD 16     // cursor padding (ints) -> one per 64B line
#define CH 4096     // edges per partition block
#define CHT 16      // edges per thread (CH / 256)
#define SCAP 6144   // build_kernel LDS edge stage (mean bucket = 4092)
// packed pair: (local_dst << 17) | src   -- requires N <= 131072

typedef __attribute__((ext_vector_type(8))) short bf16x8;
typedef __attribute__((ext_vector_type(4))) float f32x4;

__device__ inline unsigned bfr(float f) {   // fp32 -> bf16 bits, round-nearest-even
    unsigned u = __float_as_uint(f);
    return (u + 0x7FFF + ((u >> 16) & 1)) >> 16;
}
__device__ inline float uplo(unsigned p) { return __uint_as_float(p << 16); }
__device__ inline float uphi(unsigned p) { return __uint_as_float(p & 0xFFFF0000u); }

// ---------------- CSR build ----------------

__global__ __launch_bounds__(256) void hist_kernel(
        const int* __restrict__ dst, int* __restrict__ bhist, int E, int K) {
    __shared__ int lh[512];
    for (int i = threadIdx.x; i < K; i += 256) lh[i] = 0;
    __syncthreads();
    for (int e = blockIdx.x * 256 + threadIdx.x; e < E; e += gridDim.x * 256)
        atomicAdd(&lh[dst[e] >> BSH], 1);
    __syncthreads();
    for (int i = threadIdx.x; i < K; i += 256)
        if (lh[i]) atomicAdd(&bhist[i], lh[i]);
}

__global__ __launch_bounds__(512) void bscan_kernel(
        const int* __restrict__ bhist, int* __restrict__ bbase, int* __restrict__ bcur,
        int* __restrict__ rp, int K, int E, int N) {
    __shared__ int sm[512];
    int t = threadIdx.x;
    int v = (t < K) ? bhist[t] : 0;
    sm[t] = v;
    __syncthreads();
    for (int off = 1; off < 512; off <<= 1) {
        int add = (t >= off) ? sm[t - off] : 0;
        __syncthreads();
        sm[t] += add;
        __syncthreads();
    }
    if (t < K) { bbase[t] = sm[t] - v; bcur[t * BPAD] = sm[t] - v; }
    if (t == 0) { bbase[K] = E; rp[N] = E; }
}

// Block-local multi-split partition (R6: ~1-2 writebacks per pairs-line,
// independent of block->XCD placement).
__global__ __launch_bounds__(256) void partition_kernel(
        const int* __restrict__ src, const int* __restrict__ dst,
        int* __restrict__ bcur, int* __restrict__ pairs, int E) {
    __shared__ int   lcnt[512];
    __shared__ int   lstart[512];
    __shared__ int   ldelta[512];
    __shared__ int   sm[256];
    __shared__ int   staged[CH];
    __shared__ short binof[CH];
    int t = threadIdx.x;
    int base = blockIdx.x * CH;
    int n = min(CH, E - base);

    lcnt[t] = 0; lcnt[t + 256] = 0;
    __syncthreads();

    int pk[CHT]; int bn[CHT];
    #pragma unroll
    for (int j = 0; j < CHT; ++j) {
        int i = t + j * 256;
        bn[j] = -1;
        if (i < n) {
            int d = dst[base + i];
            int s = src[base + i];
            bn[j] = d >> BSH;
            pk[j] = ((d & ((1 << BSH) - 1)) << 17) | s;
            atomicAdd(&lcnt[bn[j]], 1);
        }
    }
    __syncthreads();

    int c0 = lcnt[2 * t], c1 = lcnt[2 * t + 1];
    int s2 = c0 + c1;
    sm[t] = s2;
    __syncthreads();
    for (int off = 1; off < 256; off <<= 1) {
        int add = (t >= off) ? sm[t - off] : 0;
        __syncthreads();
        sm[t] += add;
        __syncthreads();
    }
    int ex = sm[t] - s2;
    lstart[2 * t] = ex;     lstart[2 * t + 1] = ex + c0;
    lcnt[2 * t]   = ex;     lcnt[2 * t + 1]   = ex + c0;
    __syncthreads();

    #pragma unroll
    for (int j = 0; j < CHT; ++j) {
        if (bn[j] >= 0) {
            int pos = atomicAdd(&lcnt[bn[j]], 1);
            staged[pos] = pk[j];
            binof[pos] = (short)bn[j];
        }
    }
    __syncthreads();

    #pragma unroll
    for (int k = 0; k < 2; ++k) {
        int b = 2 * t + k;
        int cnt = lcnt[b] - lstart[b];
        if (cnt > 0) {
            int g = atomicAdd(&bcur[b * BPAD], cnt);
            ldelta[b] = g - lstart[b];
        }
    }
    __syncthreads();

    for (int i = t; i < n; i += 256)
        pairs[ldelta[binof[i]] + i] = staged[i];
}

// Per-bucket: count + scan + scatter; edges staged once in LDS (global
// re-read fallback past SCAP keeps correctness for any distribution).
__global__ __launch_bounds__(256) void build_kernel(
        const int* __restrict__ pairs, const int* __restrict__ bbase,
        int* __restrict__ rp, float* __restrict__ dis, int* __restrict__ col, int N) {
    __shared__ int staged[SCAP];
    __shared__ int lcnt[1 << BSH];
    __shared__ int lsum[1 << BSH];
    __shared__ int lbase[1 << BSH];
    int b = blockIdx.x;
    int t = threadIdx.x;
    int nbase = b << BSH;
    int nn = min(1 << BSH, N - nbase);
    int beg = bbase[b], end = bbase[b + 1];
    int cnt = end - beg;
    int sc = min(cnt, SCAP);
    for (int i = t; i < sc; i += 256) staged[i] = pairs[beg + i];
    if (t < 128) lcnt[t] = 0;
    __syncthreads();
    for (int i = t; i < sc; i += 256) atomicAdd(&lcnt[staged[i] >> 17], 1);
    for (int i = SCAP + t; i < cnt; i += 256) atomicAdd(&lcnt[pairs[beg + i] >> 17], 1);
    __syncthreads();
    if (t < 128) lsum[t] = lcnt[t];
    __syncthreads();
    for (int off = 1; off < 128; off <<= 1) {
        int add = (t < 128 && t >= off) ? lsum[t - off] : 0;
        __syncthreads();
        if (t < 128) lsum[t] += add;
        __syncthreads();
    }
    if (t < 128) {
        int excl = beg + lsum[t] - lcnt[t];
        lbase[t] = excl;
        if (t < nn) {
            rp[nbase + t] = excl;
            dis[nbase + t] = rsqrtf((float)(lcnt[t] + 1));  // deg incl. self-loop
        }
    }
    __syncthreads();
    if (t < 128) lcnt[t] = lbase[t];
    __syncthreads();
    for (int i = t; i < sc; i += 256) {
        int p = staged[i];
        int pos = atomicAdd(&lcnt[p >> 17], 1);
        col[pos] = p & 0x1FFFF;
    }
    for (int i = SCAP + t; i < cnt; i += 256) {
        int p = pairs[beg + i];
        int pos = atomicAdd(&lcnt[p >> 17], 1);
        col[pos] = p & 0x1FFFF;
    }
}

// ---------------- precision prep ----------------

// W[k][n] fp32 -> WT[n][k] bf16, both weights in one launch (gridDim.x = 2*FD)
__global__ void wt_kernel(const float* __restrict__ W1, unsigned short* __restrict__ W1T,
                          const float* __restrict__ W2, unsigned short* __restrict__ W2T) {
    int k = blockIdx.x & (FD - 1);
    int n = threadIdx.x;
    if (blockIdx.x < FD) W1T[n * FD + k] = (unsigned short)bfr(W1[k * FD + n]);
    else                 W2T[n * FD + k] = (unsigned short)bfr(W2[k * FD + n]);
}

// ---------------- MFMA bf16 GEMM: C = bf16( dis[row] * (A @ W) ) ----------------
// C written PLANAR: plane q = f>>6 holds features [64q, 64q+64) for all rows,
// so agg pass q touches a compact M*128B array (working-set halving).
// PLANARA: A read from planar bf16 (z1). A32: A fp32 row-major, cvt fused.

#define APAD 8
#define ASTR (FD + APAD)

template <bool A32, bool PLANARA>
__device__ void gemm_body(const void* __restrict__ Ap,
                          const unsigned short* __restrict__ WT,
                          const float* __restrict__ dis,
                          unsigned short* __restrict__ C, int M) {
    __shared__ unsigned short As[128 * ASTR];
    __shared__ unsigned short Bs[128 * ASTR];
    int tid = threadIdx.x;
    int lane = tid & 63;
    int wave = tid >> 6;
    int quad = lane >> 4;
    int l16 = lane & 15;
    int rowBase = blockIdx.x * 128;
    size_t plane = (size_t)M * 64;   // ushorts per plane

    #pragma unroll
    for (int p = 0; p < 8; ++p) {
        int r = p * 16 + (tid >> 4);
        int cq = (tid & 15) * 8;
        int gr = rowBase + r;
        uint4 v = make_uint4(0u, 0u, 0u, 0u);
        if (A32) {
            if (gr < M) {
                const float* a = (const float*)Ap + (size_t)gr * FD + cq;
                float4 f0 = *(const float4*)a;
                float4 f1 = *(const float4*)(a + 4);
                v.x = bfr(f0.x) | (bfr(f0.y) << 16);
                v.y = bfr(f0.z) | (bfr(f0.w) << 16);
                v.z = bfr(f1.x) | (bfr(f1.y) << 16);
                v.w = bfr(f1.z) | (bfr(f1.w) << 16);
            }
        } else if (PLANARA) {
            if (gr < M) {
                const unsigned short* a = (const unsigned short*)Ap
                    + (size_t)(cq >> 6) * plane + (size_t)gr * 64 + (cq & 63);
                v = *(const uint4*)a;
            }
        } else {
            if (gr < M) v = *(const uint4*)((const unsigned short*)Ap + (size_t)gr * FD + cq);
        }
        *(uint4*)&As[r * ASTR + cq] = v;
        *(uint4*)&Bs[r * ASTR + cq] = *(const uint4*)&WT[(size_t)r * FD + cq];
    }
    __syncthreads();

    int m0 = wave * 32;
    f32x4 acc[2][8] = {};
    #pragma unroll
    for (int kt = 0; kt < 4; ++kt) {
        int ko = kt * 32 + quad * 8;
        bf16x8 a0 = *(bf16x8*)&As[(m0 + l16) * ASTR + ko];
        bf16x8 a1 = *(bf16x8*)&As[(m0 + 16 + l16) * ASTR + ko];
        #pragma unroll
        for (int n = 0; n < 8; ++n) {
            bf16x8 b = *(bf16x8*)&Bs[(n * 16 + l16) * ASTR + ko];
            acc[0][n] = __builtin_amdgcn_mfma_f32_16x16x32_bf16(a0, b, acc[0][n], 0, 0, 0);
            acc[1][n] = __builtin_amdgcn_mfma_f32_16x16x32_bf16(a1, b, acc[1][n], 0, 0, 0);
        }
    }

    #pragma unroll
    for (int ms = 0; ms < 2; ++ms) {
        #pragma unroll
        for (int r = 0; r < 4; ++r) {
            int grow = rowBase + m0 + ms * 16 + quad * 4 + r;
            if (grow < M) {
                float dv = dis[grow];
                #pragma unroll
                for (int n = 0; n < 8; ++n) {
                    int f = n * 16 + l16;
                    C[(size_t)(f >> 6) * plane + (size_t)grow * 64 + (f & 63)] =
                        (unsigned short)bfr(dv * acc[ms][n][r]);
                }
            }
        }
    }
}

__global__ __launch_bounds__(256) void gemm_mfma_f32(
        const float* __restrict__ A, const unsigned short* __restrict__ WT,
        const float* __restrict__ dis, unsigned short* __restrict__ C, int M) {
    gemm_body<true, false>(A, WT, dis, C, M);
}

__global__ __launch_bounds__(256) void gemm_mfma_pl(
        const unsigned short* __restrict__ A, const unsigned short* __restrict__ WT,
        const float* __restrict__ dis, unsigned short* __restrict__ C, int M) {
    gemm_body<false, true>(A, WT, dis, C, M);
}

// ---------------- CSR aggregation + bias + ReLU ----------------
// h' planar bf16 (plane ph = features [64ph, 64ph+64), compact N*128B).
// blockIdx.y = ph; pass-0 blocks dispatch first -> passes temporally separate,
// each pass's gather working set = 6.4 MB (vs 4 MB/XCD L2).
// One wave per node: lanes 0-31 = feature half (128B coalesced gather),
// lane>>5 selects which of TWO edges; shfl_xor(32) folds.
// out[v] = relu( dis[v] * ( h'[v] + sum_u h'[u] ) + b )
// obf=1: write planar bf16 (z1, feeds gemm2); obf=0: write fp32 row-major.

__global__ __launch_bounds__(256) void agg_kernel(
        const unsigned* __restrict__ h, const float* __restrict__ dis,
        const int* __restrict__ rp, const int* __restrict__ col,
        const float2* __restrict__ bias, void* __restrict__ out, int N, int obf) {
    int v = blockIdx.x * 4 + threadIdx.y;          // blockDim = (64, 4): wave per node
    v = __builtin_amdgcn_readfirstlane(v);         // wave-uniform -> scalar rp/col loads
    if (v >= N) return;
    int ph = blockIdx.y;                           // feature-half pass
    const unsigned* hp = h + (size_t)ph * N * 32;  // plane base (32 uints/row)
    int t = threadIdx.x;                           // 0..63
    int fl = t & 31;                               // feature pair within half
    int eo = t >> 5;                               // which edge of the pair
    float2 acc = make_float2(0.f, 0.f);
    int e = rp[v];
    int end = rp[v + 1];

    for (; e + 16 <= end; e += 16) {
        int u[8];
        #pragma unroll
        for (int j = 0; j < 8; ++j) {
            int a = col[e + 2 * j];                // wave-uniform (scalar)
            int b = col[e + 2 * j + 1];
            u[j] = eo ? b : a;
        }
        unsigned p[8];
        #pragma unroll
        for (int j = 0; j < 8; ++j) p[j] = hp[(size_t)u[j] * 32 + fl];
        #pragma unroll
        for (int j = 0; j < 8; ++j) { acc.x += uplo(p[j]); acc.y += uphi(p[j]); }
    }
    for (; e + 2 <= end; e += 2) {
        int a = col[e], b = col[e + 1];
        int uu = eo ? b : a;
        unsigned p = hp[(size_t)uu * 32 + fl];
        acc.x += uplo(p); acc.y += uphi(p);
    }
    if (e < end && eo == 0) {                      // odd leftover on low half
        unsigned p = hp[(size_t)col[e] * 32 + fl];
        acc.x += uplo(p); acc.y += uphi(p);
    }

    acc.x += __shfl_xor(acc.x, 32);
    acc.y += __shfl_xor(acc.y, 32);

    if (eo == 0) {
        unsigned sp = hp[(size_t)v * 32 + fl];     // self term h'[v]
        acc.x += uplo(sp); acc.y += uphi(sp);
        float dv = dis[v];
        float2 bb = bias[32 * ph + fl];
        float2 r;
        r.x = fmaxf(fmaf(dv, acc.x, bb.x), 0.0f);
        r.y = fmaxf(fmaf(dv, acc.y, bb.y), 0.0f);
        if (obf) {
            ((unsigned*)out)[(size_t)ph * N * 32 + (size_t)v * 32 + fl] =
                bfr(r.x) | (bfr(r.y) << 16);
        } else {
            ((float2*)out)[(size_t)v * 64 + 32 * ph + fl] = r;
        }
    }
}

// ---------------- launch ----------------

extern "C" void kernel_launch(void* const* d_in, const int* in_sizes, int n_in,
                              void* d_out, int out_size, void* d_ws, size_t ws_size,
                              hipStream_t stream) {
    const float* x  = (const float*)d_in[0];
    const int*   ei = (const int*)d_in[1];   // [2, E] int32
    const float* W1 = (const float*)d_in[2];
    const float* b1 = (const float*)d_in[3];
    const float* W2 = (const float*)d_in[4];
    const float* b2 = (const float*)d_in[5];

    int N = in_sizes[0] / FD;
    int E = in_sizes[1] / 2;
    const int* src = ei;
    const int* dst = ei + E;
    int K = (N + (1 << BSH) - 1) >> BSH;     // buckets (<= 512 assumed)

    char* base = (char*)d_ws;
    size_t off = 0;
    auto align256 = [](size_t v) { return (v + 255) & ~(size_t)255; };
    int*            rp    = (int*)(base + off);            off += align256((size_t)(N + 1) * 4);
    float*          dis   = (float*)(base + off);          off += align256((size_t)N * 4);
    int*            bhist = (int*)(base + off);            off += align256(512 * 4);
    int*            bbase = (int*)(base + off);            off += align256(513 * 4);
    int*            bcur  = (int*)(base + off);            off += align256((size_t)K * BPAD * 4);
    unsigned short* w1t   = (unsigned short*)(base + off); off += align256((size_t)FD * FD * 2);
    unsigned short* w2t   = (unsigned short*)(base + off); off += align256((size_t)FD * FD * 2);
    int*            col   = (int*)(base + off);            off += align256((size_t)E * 4);
    unsigned short* hbuf  = (unsigned short*)(base + off); off += align256((size_t)N * FD * 2);
    unsigned short* z1    = (unsigned short*)(base + off); off += align256((size_t)N * FD * 2);
    int*            pairs = (int*)(base + off);            off += align256((size_t)E * 4);
    (void)ws_size; (void)n_in; (void)out_size;

    int PB = (E + CH - 1) / CH;

    (void)hipMemsetAsync(bhist, 0, 512 * 4, stream);
    hist_kernel     <<<512, 256, 0, stream>>>(dst, bhist, E, K);
    bscan_kernel    <<<1, 512, 0, stream>>>(bhist, bbase, bcur, rp, K, E, N);
    partition_kernel<<<PB, 256, 0, stream>>>(src, dst, bcur, pairs, E);
    build_kernel    <<<K, 256, 0, stream>>>(pairs, bbase, rp, dis, col, N);

    wt_kernel<<<2 * FD, FD, 0, stream>>>(W1, w1t, W2, w2t);

    dim3 aggBlk(64, 4);
    dim3 aggGrid((N + 3) / 4, 2);            // y = feature-half pass
    int gemmGrid = (N + 127) / 128;

    gemm_mfma_f32<<<gemmGrid, 256, 0, stream>>>(x, w1t, dis, hbuf, N);
    agg_kernel<<<aggGrid, aggBlk, 0, stream>>>((const unsigned*)hbuf, dis, rp, col,
                                               (const float2*)b1, z1, N, 1);
    gemm_mfma_pl <<<gemmGrid, 256, 0, stream>>>(z1, w2t, dis, hbuf, N);
    agg_kernel<<<aggGrid, aggBlk, 0, stream>>>((const unsigned*)hbuf, dis, rp, col,
                                               (const float2*)b2, d_out, N, 0);
}

// Round 12
// 258.242 us; speedup vs baseline: 1.0843x; 1.0843x over previous
//
#include <hip/hip_runtime.h>

#define FD 128      // feature dim (both layers)
#define BSH 7       // log2(nodes per bucket) = 128 nodes/bucket
#define CH 2048     // edges per partition block (782 blocks -> ~3 blocks/CU rounds)
#define CHT 8       // edges per thread (CH / 256)
#define KMAX 512    // max buckets
#define SCAP 8192   // build_kernel LDS edge stage (mean bucket = 4092, max ~4400)
// packed pair: (local_dst << 17) | src   -- requires N <= 131072

typedef __attribute__((ext_vector_type(8))) short bf16x8;
typedef __attribute__((ext_vector_type(4))) float f32x4;

__device__ inline unsigned bfr(float f) {   // fp32 -> bf16 bits, round-nearest-even
    unsigned u = __float_as_uint(f);
    return (u + 0x7FFF + ((u >> 16) & 1)) >> 16;
}
__device__ inline float uplo(unsigned p) { return __uint_as_float(p << 16); }
__device__ inline float uphi(unsigned p) { return __uint_as_float(p & 0xFFFF0000u); }

// ---------------- CSR build ----------------
// R12 scheme: each partition block multi-splits its CH-edge chunk in LDS and
// writes it back SEQUENTIALLY (bucket-sorted within the chunk) -> 1.0x write
// density with zero cross-block line sharing, independent of XCD placement.
// Per-block bucket boundaries go to lstartG; bucket totals accumulate via one
// atomicAdd per (block,bucket). hist/bscan kernels are eliminated.

__global__ __launch_bounds__(256) void partition_kernel(
        const int* __restrict__ src, const int* __restrict__ dst,
        int* __restrict__ lstartG, int* __restrict__ total,
        int* __restrict__ pairs, int E, int K) {
    __shared__ int lcnt[KMAX];     // counts, then scatter cursor
    __shared__ int lstart[KMAX];   // local exclusive prefix
    __shared__ int sm[256];
    __shared__ int staged[CH];
    int t = threadIdx.x;
    int base = blockIdx.x * CH;
    int n = min(CH, E - base);

    lcnt[t] = 0; lcnt[t + 256] = 0;
    __syncthreads();

    int pk[CHT]; int bn[CHT];
    #pragma unroll
    for (int j = 0; j < CHT; ++j) {
        int i = t + j * 256;
        bn[j] = -1;
        if (i < n) {
            int d = dst[base + i];
            int s = src[base + i];
            bn[j] = d >> BSH;
            pk[j] = ((d & ((1 << BSH) - 1)) << 17) | s;
            atomicAdd(&lcnt[bn[j]], 1);
        }
    }
    __syncthreads();

    // exclusive scan of 512 bins, 2 consecutive bins per thread
    int c0 = lcnt[2 * t], c1 = lcnt[2 * t + 1];
    int s2 = c0 + c1;
    sm[t] = s2;
    __syncthreads();
    for (int off = 1; off < 256; off <<= 1) {
        int add = (t >= off) ? sm[t - off] : 0;
        __syncthreads();
        sm[t] += add;
        __syncthreads();
    }
    int ex = sm[t] - s2;
    lstart[2 * t] = ex;     lstart[2 * t + 1] = ex + c0;
    lcnt[2 * t]   = ex;     lcnt[2 * t + 1]   = ex + c0;   // cursor
    __syncthreads();

    // scatter chunk into staged[], sorted by bucket
    #pragma unroll
    for (int j = 0; j < CHT; ++j) {
        if (bn[j] >= 0) {
            int pos = atomicAdd(&lcnt[bn[j]], 1);
            staged[pos] = pk[j];
        }
    }
    __syncthreads();

    // sequential coalesced copy-out: this block owns pairs[base .. base+n)
    for (int i = t; i < n; i += 256)
        pairs[base + i] = staged[i];

    // per-block bucket boundaries + bucket totals
    size_t lrow = (size_t)blockIdx.x * (K + 1);
    for (int b = t; b < K; b += 256) {
        lstartG[lrow + b] = lstart[b];
        int c = lcnt[b] - lstart[b];
        if (c) atomicAdd(&total[b], c);
    }
    if (t == 0) lstartG[lrow + K] = n;
}

// exclusive scan of K bucket totals -> bbase; also rp[N]=E
__global__ __launch_bounds__(512) void totscan_kernel(
        const int* __restrict__ total, int* __restrict__ bbase,
        int* __restrict__ rp, int K, int E, int N) {
    __shared__ int sm[512];
    int t = threadIdx.x;
    int v = (t < K) ? total[t] : 0;
    sm[t] = v;
    __syncthreads();
    for (int off = 1; off < 512; off <<= 1) {
        int add = (t >= off) ? sm[t - off] : 0;
        __syncthreads();
        sm[t] += add;
        __syncthreads();
    }
    if (t < K) bbase[t] = sm[t] - v;
    if (t == 0) { bbase[K] = E; rp[N] = E; }
}

// Per-bucket: gather this bucket's fragments (thread-per-fragment) into LDS,
// then count + scan + scatter; writes rp/dis/col. col writes confined to the
// bucket's contiguous region -> dense.
__global__ __launch_bounds__(256) void build_kernel(
        const int* __restrict__ pairs, const int* __restrict__ lstartG,
        const int* __restrict__ bbase, int* __restrict__ rp,
        float* __restrict__ dis, int* __restrict__ col, int N, int PB, int K) {
    __shared__ int staged[SCAP];
    __shared__ int lcnt[1 << BSH];
    __shared__ int lsum[1 << BSH];
    __shared__ int lbase[1 << BSH];
    __shared__ int sm[256];
    int b = blockIdx.x;
    int t = threadIdx.x;
    int nbase = b << BSH;
    int nn = min(1 << BSH, N - nbase);
    int beg = bbase[b];
    int cnt = bbase[b + 1] - beg;

    // fragment descriptors for this thread (p = t, t+256, ...; <= 4)
    int fp[4], fl0[4], flen[4];
    int nf = 0, mysum = 0;
    for (int p = t; p < PB; p += 256) {
        size_t lrow = (size_t)p * (K + 1);
        int l0 = lstartG[lrow + b];
        int l1 = lstartG[lrow + b + 1];
        fp[nf] = p; fl0[nf] = l0; flen[nf] = l1 - l0;
        mysum += l1 - l0;
        ++nf;
    }
    // exclusive scan of per-thread sums -> dest offsets in staged
    sm[t] = mysum;
    __syncthreads();
    for (int off = 1; off < 256; off <<= 1) {
        int add = (t >= off) ? sm[t - off] : 0;
        __syncthreads();
        sm[t] += add;
        __syncthreads();
    }
    int o = sm[t] - mysum;

    if (t < 128) lcnt[t] = 0;

    if (cnt <= SCAP) {   // fast path (always, for Poisson buckets)
        for (int f = 0; f < nf; ++f) {
            int gbase = fp[f] * CH + fl0[f];
            for (int i = 0; i < flen[f]; ++i) staged[o + i] = pairs[gbase + i];
            o += flen[f];
        }
        __syncthreads();
        for (int i = t; i < cnt; i += 256) atomicAdd(&lcnt[staged[i] >> 17], 1);
    } else {             // overflow fallback: count directly from global
        __syncthreads();
        for (int f = 0; f < nf; ++f) {
            int gbase = fp[f] * CH + fl0[f];
            for (int i = 0; i < flen[f]; ++i)
                atomicAdd(&lcnt[pairs[gbase + i] >> 17], 1);
        }
    }
    __syncthreads();

    if (t < 128) lsum[t] = lcnt[t];
    __syncthreads();
    for (int off = 1; off < 128; off <<= 1) {
        int add = (t < 128 && t >= off) ? lsum[t - off] : 0;
        __syncthreads();
        if (t < 128) lsum[t] += add;
        __syncthreads();
    }
    if (t < 128) {
        int excl = beg + lsum[t] - lcnt[t];
        lbase[t] = excl;
        if (t < nn) {
            rp[nbase + t] = excl;
            dis[nbase + t] = rsqrtf((float)(lcnt[t] + 1));  // deg incl. self-loop
        }
    }
    __syncthreads();
    if (t < 128) lcnt[t] = lbase[t];   // reuse as cursor
    __syncthreads();

    if (cnt <= SCAP) {
        for (int i = t; i < cnt; i += 256) {
            int p = staged[i];
            int pos = atomicAdd(&lcnt[p >> 17], 1);
            col[pos] = p & 0x1FFFF;
        }
    } else {
        for (int f = 0; f < nf; ++f) {
            int gbase = fp[f] * CH + fl0[f];
            for (int i = 0; i < flen[f]; ++i) {
                int p = pairs[gbase + i];
                int pos = atomicAdd(&lcnt[p >> 17], 1);
                col[pos] = p & 0x1FFFF;
            }
        }
    }
}

// ---------------- precision prep ----------------

// W[k][n] fp32 -> WT[n][k] bf16, both weights in one launch (gridDim.x = 2*FD)
__global__ void wt_kernel(const float* __restrict__ W1, unsigned short* __restrict__ W1T,
                          const float* __restrict__ W2, unsigned short* __restrict__ W2T) {
    int k = blockIdx.x & (FD - 1);
    int n = threadIdx.x;
    if (blockIdx.x < FD) W1T[n * FD + k] = (unsigned short)bfr(W1[k * FD + n]);
    else                 W2T[n * FD + k] = (unsigned short)bfr(W2[k * FD + n]);
}

// ---------------- MFMA bf16 GEMM: C = bf16( dis[row] * (A @ W) ) ----------------
// WT: [128 x 128] bf16, WT[n][k]. Block: 128 rows, full K=N=128 in LDS.
// 4 waves, 32 rows each. Mappings (guide-verified): A[m=lane&15][k=quad*8+j],
// B[k=quad*8+j][n=lane&15], C/D row=quad*4+reg, col=lane&15.
// A32 variant: A is fp32, converted to bf16 during staging (fuses cvt pass).

#define APAD 8
#define ASTR (FD + APAD)

template <bool A32>
__device__ void gemm_body(const void* __restrict__ Ap,
                          const unsigned short* __restrict__ WT,
                          const float* __restrict__ dis,
                          unsigned short* __restrict__ C, int M) {
    __shared__ unsigned short As[128 * ASTR];
    __shared__ unsigned short Bs[128 * ASTR];
    int tid = threadIdx.x;
    int lane = tid & 63;
    int wave = tid >> 6;
    int quad = lane >> 4;
    int l16 = lane & 15;
    int rowBase = blockIdx.x * 128;

    #pragma unroll
    for (int p = 0; p < 8; ++p) {
        int r = p * 16 + (tid >> 4);
        int cq = (tid & 15) * 8;
        int gr = rowBase + r;
        uint4 v = make_uint4(0u, 0u, 0u, 0u);
        if (A32) {
            if (gr < M) {
                const float* a = (const float*)Ap + (size_t)gr * FD + cq;
                float4 f0 = *(const float4*)a;
                float4 f1 = *(const float4*)(a + 4);
                v.x = bfr(f0.x) | (bfr(f0.y) << 16);
                v.y = bfr(f0.z) | (bfr(f0.w) << 16);
                v.z = bfr(f1.x) | (bfr(f1.y) << 16);
                v.w = bfr(f1.z) | (bfr(f1.w) << 16);
            }
        } else {
            if (gr < M) v = *(const uint4*)((const unsigned short*)Ap + (size_t)gr * FD + cq);
        }
        *(uint4*)&As[r * ASTR + cq] = v;
        *(uint4*)&Bs[r * ASTR + cq] = *(const uint4*)&WT[(size_t)r * FD + cq];
    }
    __syncthreads();

    int m0 = wave * 32;
    f32x4 acc[2][8] = {};
    #pragma unroll
    for (int kt = 0; kt < 4; ++kt) {
        int ko = kt * 32 + quad * 8;
        bf16x8 a0 = *(bf16x8*)&As[(m0 + l16) * ASTR + ko];
        bf16x8 a1 = *(bf16x8*)&As[(m0 + 16 + l16) * ASTR + ko];
        #pragma unroll
        for (int n = 0; n < 8; ++n) {
            bf16x8 b = *(bf16x8*)&Bs[(n * 16 + l16) * ASTR + ko];
            acc[0][n] = __builtin_amdgcn_mfma_f32_16x16x32_bf16(a0, b, acc[0][n], 0, 0, 0);
            acc[1][n] = __builtin_amdgcn_mfma_f32_16x16x32_bf16(a1, b, acc[1][n], 0, 0, 0);
        }
    }

    #pragma unroll
    for (int ms = 0; ms < 2; ++ms) {
        #pragma unroll
        for (int r = 0; r < 4; ++r) {
            int grow = rowBase + m0 + ms * 16 + quad * 4 + r;
            if (grow < M) {
                float dv = dis[grow];
                #pragma unroll
                for (int n = 0; n < 8; ++n) {
                    C[(size_t)grow * FD + n * 16 + l16] =
                        (unsigned short)bfr(dv * acc[ms][n][r]);
                }
            }
        }
    }
}

__global__ __launch_bounds__(256) void gemm_mfma_f32(
        const float* __restrict__ A, const unsigned short* __restrict__ WT,
        const float* __restrict__ dis, unsigned short* __restrict__ C, int M) {
    gemm_body<true>(A, WT, dis, C, M);
}

__global__ __launch_bounds__(256) void gemm_mfma_bf16(
        const unsigned short* __restrict__ A, const unsigned short* __restrict__ WT,
        const float* __restrict__ dis, unsigned short* __restrict__ C, int M) {
    gemm_body<false>(A, WT, dis, C, M);
}

// ---------------- CSR aggregation + bias + ReLU ----------------
// R10 form (proven optimum): h' pre-scaled by dis, stored bf16 row-major
// (2 per uint). One node per wave, lane t = features [2t,2t+1], plain cached
// loads, 16 edges in flight. out[v] = relu(dis[v]*(h'[v]+sum_u h'[u]) + b).
// obf=1: write packed bf16 (z1, feeds gemm2); obf=0: write fp32 (final out).

__global__ __launch_bounds__(256) void agg_kernel(
        const unsigned* __restrict__ h, const float* __restrict__ dis,
        const int* __restrict__ rp, const int* __restrict__ col,
        const float2* __restrict__ bias, void* __restrict__ out, int N, int obf) {
    int v = blockIdx.x * 4 + threadIdx.y;          // blockDim = (64, 4): wave per node
    v = __builtin_amdgcn_readfirstlane(v);         // wave-uniform -> scalar rp/col loads
    if (v >= N) return;
    int t = threadIdx.x;                           // 0..63
    float dv = dis[v];
    size_t vb = (size_t)v * 64 + t;
    unsigned hp = h[vb];                           // self term h'[v]
    float2 acc;
    acc.x = uplo(hp); acc.y = uphi(hp);
    int e = rp[v];
    int end = rp[v + 1];

    for (; e + 16 <= end; e += 16) {
        int u[16];
        #pragma unroll
        for (int j = 0; j < 16; ++j) u[j] = col[e + j];   // wave-uniform scalar loads
        unsigned p[16];
        #pragma unroll
        for (int j = 0; j < 16; ++j) p[j] = h[(size_t)u[j] * 64 + t];
        #pragma unroll
        for (int j = 0; j < 16; ++j) {
            acc.x += uplo(p[j]); acc.y += uphi(p[j]);
        }
    }
    for (; e + 4 <= end; e += 4) {
        int u0 = col[e], u1 = col[e + 1], u2 = col[e + 2], u3 = col[e + 3];
        unsigned p0 = h[(size_t)u0 * 64 + t];
        unsigned p1 = h[(size_t)u1 * 64 + t];
        unsigned p2 = h[(size_t)u2 * 64 + t];
        unsigned p3 = h[(size_t)u3 * 64 + t];
        acc.x += uplo(p0); acc.y += uphi(p0);
        acc.x += uplo(p1); acc.y += uphi(p1);
        acc.x += uplo(p2); acc.y += uphi(p2);
        acc.x += uplo(p3); acc.y += uphi(p3);
    }
    for (; e < end; ++e) {
        unsigned p = h[(size_t)col[e] * 64 + t];
        acc.x += uplo(p); acc.y += uphi(p);
    }

    float2 bb = bias[t];
    float2 r;
    r.x = fmaxf(fmaf(dv, acc.x, bb.x), 0.0f);
    r.y = fmaxf(fmaf(dv, acc.y, bb.y), 0.0f);
    if (obf) {
        ((unsigned*)out)[vb] = bfr(r.x) | (bfr(r.y) << 16);
    } else {
        ((float2*)out)[vb] = r;
    }
}

// ---------------- launch ----------------

extern "C" void kernel_launch(void* const* d_in, const int* in_sizes, int n_in,
                              void* d_out, int out_size, void* d_ws, size_t ws_size,
                              hipStream_t stream) {
    const float* x  = (const float*)d_in[0];
    const int*   ei = (const int*)d_in[1];   // [2, E] int32
    const float* W1 = (const float*)d_in[2];
    const float* b1 = (const float*)d_in[3];
    const float* W2 = (const float*)d_in[4];
    const float* b2 = (const float*)d_in[5];

    int N = in_sizes[0] / FD;
    int E = in_sizes[1] / 2;
    const int* src = ei;
    const int* dst = ei + E;
    int K = (N + (1 << BSH) - 1) >> BSH;     // buckets (<= 512 assumed)
    int PB = (E + CH - 1) / CH;              // partition blocks

    char* base = (char*)d_ws;
    size_t off = 0;
    auto align256 = [](size_t v) { return (v + 255) & ~(size_t)255; };
    int*            rp    = (int*)(base + off);            off += align256((size_t)(N + 1) * 4);
    float*          dis   = (float*)(base + off);          off += align256((size_t)N * 4);
    int*            total = (int*)(base + off);            off += align256(512 * 4);
    int*            bbase = (int*)(base + off);            off += align256(513 * 4);
    unsigned short* w1t   = (unsigned short*)(base + off); off += align256((size_t)FD * FD * 2);
    unsigned short* w2t   = (unsigned short*)(base + off); off += align256((size_t)FD * FD * 2);
    int*            col   = (int*)(base + off);            off += align256((size_t)E * 4);
    unsigned short* hbuf  = (unsigned short*)(base + off); off += align256((size_t)N * FD * 2);
    unsigned short* z1    = (unsigned short*)(base + off); off += align256((size_t)N * FD * 2);
    int*            pairs = (int*)(base + off);            off += align256((size_t)E * 4);
    int*            lstartG = (int*)hbuf;   // overlay: dead until build completes,
                                            // gemm1 (first hbuf writer) runs after.
    (void)ws_size; (void)n_in; (void)out_size;

    (void)hipMemsetAsync(total, 0, 512 * 4, stream);
    partition_kernel<<<PB, 256, 0, stream>>>(src, dst, lstartG, total, pairs, E, K);
    totscan_kernel  <<<1, 512, 0, stream>>>(total, bbase, rp, K, E, N);
    build_kernel    <<<K, 256, 0, stream>>>(pairs, lstartG, bbase, rp, dis, col, N, PB, K);

    wt_kernel<<<2 * FD, FD, 0, stream>>>(W1, w1t, W2, w2t);

    dim3 aggBlk(64, 4);
    int aggGrid = (N + 3) / 4;
    int gemmGrid = (N + 127) / 128;

    gemm_mfma_f32 <<<gemmGrid, 256, 0, stream>>>(x, w1t, dis, hbuf, N);
    agg_kernel<<<aggGrid, aggBlk, 0, stream>>>((const unsigned*)hbuf, dis, rp, col,
                                               (const float2*)b1, z1, N, 1);
    gemm_mfma_bf16<<<gemmGrid, 256, 0, stream>>>(z1, w2t, dis, hbuf, N);
    agg_kernel<<<aggGrid, aggBlk, 0, stream>>>((const unsigned*)hbuf, dis, rp, col,
                                               (const float2*)b2, d_out, N, 0);
}